// Round 2
// baseline (669.629 us; speedup 1.0000x reference)
//
#include <hip/hip_runtime.h>
#include <stdint.h>

#define N_PTS 524288
#define DQ 64
#define HQ 256
#define WQ 256
#define MAP_BYTES (2*DQ*HQ*WQ*4)   /* 33554432 */
#define NBKT 4096                  /* buckets = mbase >> 11 */

typedef short bf8  __attribute__((ext_vector_type(8)));
typedef float f16v __attribute__((ext_vector_type(16)));

static __device__ __forceinline__ short f2bf(float f) {
    union { float f; uint32_t u; } v; v.f = f;
    return (short)((v.u + 0x7fffu + ((v.u >> 16) & 1u)) >> 16);
}
static __device__ __forceinline__ float fast_sigmoid(float x) {
    return 1.f / (1.f + __expf(-x));
}
static __device__ __forceinline__ float fast_tanh(float x) {
    return 1.f - 2.f / (__expf(2.f * x) + 1.f);
}

// ---- spatial counting sort: histogram over linearized coordinate ----
__global__ void k_hist(const int* __restrict__ coors, int* __restrict__ hist) {
    int n = blockIdx.x * 256 + threadIdx.x;
    int4 c = ((const int4*)coors)[n];
    int mbase = ((c.x*DQ + c.y)*HQ + c.z)*WQ + c.w;
    atomicAdd(&hist[mbase >> 11], 1);
}

// single-block exclusive prefix sum over NBKT counts (in place)
__global__ void k_scan(int* __restrict__ hist) {
    __shared__ int wsum[4];
    int tid = threadIdx.x;
    int lane = tid & 63, wv = tid >> 6;
    int v[16]; int s = 0;
    #pragma unroll
    for (int i = 0; i < 16; i++) { v[i] = hist[tid*16 + i]; s += v[i]; }
    int sc = s;
    #pragma unroll
    for (int d = 1; d < 64; d <<= 1) {
        int t = __shfl_up(sc, d, 64);
        if (lane >= d) sc += t;
    }
    if (lane == 63) wsum[wv] = sc;
    __syncthreads();
    int base = 0;
    #pragma unroll
    for (int w = 0; w < 4; w++) if (w < wv) base += wsum[w];
    int excl = base + sc - s;
    #pragma unroll
    for (int i = 0; i < 16; i++) { int c = v[i]; hist[tid*16 + i] = excl; excl += c; }
}

// fused: rank assignment + bf16 feature pack into sorted slot + map/sorg scatter
__global__ void k_feats(const float* __restrict__ xf, const float* __restrict__ hf,
                        const int* __restrict__ coors, int* __restrict__ hist,
                        short* __restrict__ fb, int* __restrict__ map,
                        int* __restrict__ sorg) {
    int t = blockIdx.x * 256 + threadIdx.x;           // t < N*8
    int n = t >> 3, seg = t & 7;
    int lane = threadIdx.x & 63;
    int slot = 0;
    if (seg == 0) {
        int4 c = ((const int4*)coors)[n];
        int mb = ((c.x*DQ + c.y)*HQ + c.z)*WQ + c.w;
        slot = atomicAdd(&hist[mb >> 11], 1);
        map[mb] = slot;
        sorg[slot] = n;
    }
    slot = __shfl(slot, lane & 56, 64);               // broadcast from seg==0 lane
    const float* src = (seg < 4) ? (xf + n*32 + seg*8) : (hf + n*32 + seg*8 - 32);
    float4 a = ((const float4*)src)[0];
    float4 b = ((const float4*)src)[1];
    bf8 rv;
    rv[0]=f2bf(a.x); rv[1]=f2bf(a.y); rv[2]=f2bf(a.z); rv[3]=f2bf(a.w);
    rv[4]=f2bf(b.x); rv[5]=f2bf(b.y); rv[6]=f2bf(b.z); rv[7]=f2bf(b.w);
    ((bf8*)fb)[slot*8 + seg] = rv;
}

__global__ void k_wt(const float* __restrict__ w, short* __restrict__ wt) {
    int t = blockIdx.x * 256 + threadIdx.x;
    if (t >= 27*64*128) return;
    int jj = t & 7, c = (t >> 3) & 127, jg = (t >> 10) & 7, k = t >> 13;
    int j = jg*8 + jj;
    wt[t] = f2bf(w[(k*64 + j)*128 + c]);              // Wt[k][jg][c][jj] = W[k][j][c]
}

__launch_bounds__(256, 2)
__global__ void k_main(const int* __restrict__ map, const short* __restrict__ fb,
                       const short* __restrict__ wt, const float* __restrict__ bias,
                       const float* __restrict__ cfeat, const int* __restrict__ coors,
                       const int* __restrict__ sorg, const short* __restrict__ zp,
                       float* __restrict__ out)
{
    const int tid  = threadIdx.x;
    const int lane = tid & 63;
    const int wv   = tid >> 6;
    const int l31  = lane & 31;
    const int lhi  = lane >> 5;

    // chunked XCD swizzle: blocks with bid%8==x (XCD x) get a contiguous sorted range
    const int bid   = (blockIdx.x & 7) * 256 + (blockIdx.x >> 3);   // nwg = 2048 = 8*256
    const int pbase = bid * 256;
    const int p     = pbase + wv*64 + lane;

    const int orig = sorg[p];
    const int4 cr = ((const int4*)coors)[orig];   // b,z,y,x
    const int mbase = ((cr.x*DQ + cr.y)*HQ + cr.z)*WQ + cr.w;

    auto probe = [&](int ko) -> int {
        int dz = ko/9 - 1, dy = (ko/3)%3 - 1, dxo = ko%3 - 1;
        if ((unsigned)(cr.y + dz) < (unsigned)DQ &&
            (unsigned)(cr.z + dy) < (unsigned)HQ &&
            (unsigned)(cr.w + dxo) < (unsigned)WQ)
            return map[mbase + (dz*HQ + dy)*WQ + dxo];
        return -1;
    };

    // direct register gather of this lane's A fragments for one offset:
    // dst[j]   = row n0 chunk (2j+lhi), dst[4+j] = row n1 chunk (2j+lhi)
    auto gather = [&](int n0, int n1, bf8* dst) {
        const short* s0 = (n0 >= 0) ? (fb + (size_t)n0*64 + lhi*8) : (zp + lhi*8);
        const short* s1 = (n1 >= 0) ? (fb + (size_t)n1*64 + lhi*8) : (zp + lhi*8);
        #pragma unroll
        for (int j = 0; j < 4; j++) {
            dst[j]     = *(const bf8*)(s0 + j*16);
            dst[4 + j] = *(const bf8*)(s1 + j*16);
        }
    };

    f16v acc[2][4];
    #pragma unroll
    for (int mt = 0; mt < 2; mt++)
        #pragma unroll
        for (int ct = 0; ct < 4; ct++) {
            float bv = bias[ct*32 + l31];
            #pragma unroll
            for (int r = 0; r < 16; r++) acc[mt][ct][r] = bv;
        }

    // ---- prologue: prime probes, first gathers ----
    int pA = probe(0);
    int pB = probe(1);
    int pr_old = probe(2);

    bf8 a_cur[8], a_next[8];
    {
        int g0 = __shfl(pA, l31, 64);
        int g1 = __shfl(pA, l31 + 32, 64);
        gather(g0, g1, a_cur);
    }
    int g0n = __shfl(pB, l31, 64);
    int g1n = __shfl(pB, l31 + 32, 64);

    #pragma unroll 1
    for (int ko = 0; ko < 27; ko++) {
        if (ko < 26) gather(g0n, g1n, a_next);   // plain loads, used next iter
        int pr_new = (ko < 24) ? probe(ko + 3) : -1;

        // ---- MFMA phase: a from regs, b direct from global (L1/L2-resident wt) ----
        const short* wko = wt + ko*8192;
        #pragma unroll
        for (int ks = 0; ks < 4; ks++) {
            int jg = ks*2 + lhi;
            const short* wb = wko + (jg*128 + l31)*8;
            #pragma unroll
            for (int ct = 0; ct < 4; ct++) {
                bf8 b = *(const bf8*)(wb + ct*32*8);
                acc[0][ct] = __builtin_amdgcn_mfma_f32_32x32x16_bf16(a_cur[ks],     b, acc[0][ct], 0, 0, 0);
                acc[1][ct] = __builtin_amdgcn_mfma_f32_32x32x16_bf16(a_cur[4 + ks], b, acc[1][ct], 0, 0, 0);
            }
        }

        if (ko < 25) {                    // nids for data (ko+2), used next iter
            g0n = __shfl(pr_old, l31, 64);
            g1n = __shfl(pr_old, l31 + 32, 64);
            pr_old = pr_new;
        }
        #pragma unroll
        for (int j = 0; j < 8; j++) a_cur[j] = a_next[j];
    }

    // ---- epilogue: LSTM gates, lane-local; scatter to original point ids ----
    #pragma unroll
    for (int mt = 0; mt < 2; mt++) {
        #pragma unroll
        for (int r = 0; r < 16; r++) {
            int row = (r & 3) + 8*(r >> 2) + 4*lhi;
            int pp  = pbase + wv*64 + mt*32 + row;
            int opp = sorg[pp];
            float gi = acc[mt][0][r];
            float gf = acc[mt][1][r];
            float go = acc[mt][2][r];
            float gg = acc[mt][3][r];
            float cv = cfeat[opp*32 + l31];
            float si = fast_sigmoid(gi);
            float sf = fast_sigmoid(gf);
            float so = fast_sigmoid(go);
            float tg = fast_tanh(gg);
            float cn = sf*cv + si*tg;
            float hn = so * fast_tanh(cn);
            out[opp*32 + l31] = hn;
            out[N_PTS*32 + opp*32 + l31] = cn;
        }
    }
}

extern "C" void kernel_launch(void* const* d_in, const int* in_sizes, int n_in,
                              void* d_out, int out_size, void* d_ws, size_t ws_size,
                              hipStream_t stream) {
    const float* xf    = (const float*)d_in[0];
    const float* hf    = (const float*)d_in[1];
    const float* cf    = (const float*)d_in[2];
    const float* w     = (const float*)d_in[3];
    const float* bias  = (const float*)d_in[4];
    const int*   coors = (const int*)d_in[5];
    float* out = (float*)d_out;

    char* base = (char*)d_ws;
    int*   map    = (int*)base;                                        // 33554432 B
    short* fb     = (short*)(base + MAP_BYTES);                        // 67108864 B
    short* wtb    = (short*)(base + 100663296);                        //   442368 B
    short* zp     = (short*)(base + 101105664);                        //      512 B
    int*   sorg   = (int*)(base + 101106176);                          //  2097152 B
    int*   hist   = (int*)(base + 103203328);                          //    16384 B

    hipMemsetAsync(map, 0xFF, MAP_BYTES, stream);                      // map = -1
    hipMemsetAsync(hist, 0, NBKT*4, stream);
    hipMemsetAsync(zp, 0, 256, stream);                                // zero row
    k_hist<<<N_PTS/256, 256, 0, stream>>>(coors, hist);
    k_scan<<<1, 256, 0, stream>>>(hist);
    k_feats<<<(N_PTS*8)/256, 256, 0, stream>>>(xf, hf, coors, hist, fb, map, sorg);
    k_wt<<<(27*64*128 + 255)/256, 256, 0, stream>>>(w, wtb);
    k_main<<<N_PTS/256, 256, 0, stream>>>(map, fb, wtb, bias, cf, coors, sorg, zp, out);
}

// Round 3
// 568.204 us; speedup vs baseline: 1.1785x; 1.1785x over previous
//
#include <hip/hip_runtime.h>
#include <stdint.h>

#define N_PTS 524288
#define DQ 64
#define HQ 256
#define WQ 256
#define MAP_BYTES (2*DQ*HQ*WQ*4)   /* 33554432 */
#define NBKT 4096                  /* buckets = mbase >> 11 */

typedef short bf8  __attribute__((ext_vector_type(8)));
typedef float f16v __attribute__((ext_vector_type(16)));

static __device__ __forceinline__ short f2bf(float f) {
    union { float f; uint32_t u; } v; v.f = f;
    return (short)((v.u + 0x7fffu + ((v.u >> 16) & 1u)) >> 16);
}
static __device__ __forceinline__ float fast_sigmoid(float x) {
    return 1.f / (1.f + __expf(-x));
}
static __device__ __forceinline__ float fast_tanh(float x) {
    return 1.f - 2.f / (__expf(2.f * x) + 1.f);
}

// fused: bf16 feature pack (original order, coalesced) + map scatter + bucket histogram
__global__ void k_feats(const float* __restrict__ xf, const float* __restrict__ hf,
                        const int* __restrict__ coors, int* __restrict__ hist,
                        short* __restrict__ fb, int* __restrict__ map) {
    int t = blockIdx.x * 256 + threadIdx.x;           // t < N*8
    int n = t >> 3, seg = t & 7;
    const float* src = (seg < 4) ? (xf + n*32 + seg*8) : (hf + n*32 + seg*8 - 32);
    float4 a = ((const float4*)src)[0];
    float4 b = ((const float4*)src)[1];
    bf8 rv;
    rv[0]=f2bf(a.x); rv[1]=f2bf(a.y); rv[2]=f2bf(a.z); rv[3]=f2bf(a.w);
    rv[4]=f2bf(b.x); rv[5]=f2bf(b.y); rv[6]=f2bf(b.z); rv[7]=f2bf(b.w);
    ((bf8*)fb)[t] = rv;
    if (seg == 0) {
        int4 c = ((const int4*)coors)[n];
        int mb = ((c.x*DQ + c.y)*HQ + c.z)*WQ + c.w;
        map[mb] = n;                                  // map stores ORIGINAL point id
        atomicAdd(&hist[mb >> 11], 1);
    }
}

// single-block exclusive prefix sum over NBKT counts (in place)
__global__ void k_scan(int* __restrict__ hist) {
    __shared__ int wsum[4];
    int tid = threadIdx.x;
    int lane = tid & 63, wv = tid >> 6;
    int v[16]; int s = 0;
    #pragma unroll
    for (int i = 0; i < 16; i++) { v[i] = hist[tid*16 + i]; s += v[i]; }
    int sc = s;
    #pragma unroll
    for (int d = 1; d < 64; d <<= 1) {
        int t = __shfl_up(sc, d, 64);
        if (lane >= d) sc += t;
    }
    if (lane == 63) wsum[wv] = sc;
    __syncthreads();
    int base = 0;
    #pragma unroll
    for (int w = 0; w < 4; w++) if (w < wv) base += wsum[w];
    int excl = base + sc - s;
    #pragma unroll
    for (int i = 0; i < 16; i++) { int c = v[i]; hist[tid*16 + i] = excl; excl += c; }
}

// sorted processing order: sorg[slot] = original point id
__global__ void k_rank(const int* __restrict__ coors, int* __restrict__ hist,
                       int* __restrict__ sorg) {
    int n = blockIdx.x * 256 + threadIdx.x;
    int4 c = ((const int4*)coors)[n];
    int mb = ((c.x*DQ + c.y)*HQ + c.z)*WQ + c.w;
    int slot = atomicAdd(&hist[mb >> 11], 1);
    sorg[slot] = n;
}

__global__ void k_wt(const float* __restrict__ w, short* __restrict__ wt) {
    int t = blockIdx.x * 256 + threadIdx.x;
    if (t >= 27*64*128) return;
    int jj = t & 7, c = (t >> 3) & 127, jg = (t >> 10) & 7, k = t >> 13;
    int j = jg*8 + jj;
    wt[t] = f2bf(w[(k*64 + j)*128 + c]);              // Wt[k][jg][c][jj] = W[k][j][c]
}

__launch_bounds__(256, 2)
__global__ void k_main(const int* __restrict__ map, const short* __restrict__ fb,
                       const short* __restrict__ wt, const float* __restrict__ bias,
                       const float* __restrict__ cfeat, const int* __restrict__ coors,
                       const int* __restrict__ sorg, const short* __restrict__ zp,
                       float* __restrict__ out)
{
    __shared__ short Wlds[2][8192];   // double-buffered W slice: 2 x 16 kB

    const int tid  = threadIdx.x;
    const int lane = tid & 63;
    const int wv   = tid >> 6;
    const int l31  = lane & 31;
    const int lhi  = lane >> 5;

    // chunked XCD swizzle: blocks with bid%8==x (XCD x) get a contiguous sorted range
    const int bid   = (blockIdx.x & 7) * 256 + (blockIdx.x >> 3);   // nwg = 2048 = 8*256
    const int pbase = bid * 256;
    const int p     = pbase + wv*64 + lane;

    const int orig = sorg[p];
    const int4 cr = ((const int4*)coors)[orig];   // b,z,y,x
    const int mbase_zyx = cr.x*DQ + cr.y;

    // branch-free probe: ALWAYS issues exactly one load (clamp + select).
    // (exec-masked skip would break the counted vmcnt below.)
    auto probe = [&](int ko) -> int {
        int dz = ko/9 - 1, dy = (ko/3)%3 - 1, dxo = ko%3 - 1;
        int nz = cr.y + dz, ny = cr.z + dy, nx = cr.w + dxo;
        bool inb = ((unsigned)nz < (unsigned)DQ) & ((unsigned)ny < (unsigned)HQ) &
                   ((unsigned)nx < (unsigned)WQ);
        int cz = min(max(nz, 0), DQ-1);
        int cy = min(max(ny, 0), HQ-1);
        int cx = min(max(nx, 0), WQ-1);
        int nid = map[((cr.x*DQ + cz)*HQ + cy)*WQ + cx];
        return inb ? nid : -1;
    };

    // async stage of W[ko] (16 kB) into Wlds[ko&1]; exactly 4 vmem ops per wave
    auto stageW = [&](int ko) {
        const short* src = wt + ko*8192;
        #pragma unroll
        for (int i = 0; i < 4; i++) {
            int cb = i*256 + wv*64;          // 16B-chunk base for this wave
            __builtin_amdgcn_global_load_lds(
                (const __attribute__((address_space(1))) void*)(src + (size_t)(cb + lane)*8),
                (__attribute__((address_space(3))) void*)&Wlds[ko & 1][cb*8],
                16, 0, 0);
        }
    };

    // register gather of A fragments; exactly 8 vmem ops (pointer-select, no branch)
    auto gather = [&](int n0, int n1, bf8* dst) {
        const short* s0 = (n0 >= 0) ? (fb + (size_t)n0*64 + lhi*8) : (zp + lhi*8);
        const short* s1 = (n1 >= 0) ? (fb + (size_t)n1*64 + lhi*8) : (zp + lhi*8);
        #pragma unroll
        for (int j = 0; j < 4; j++) {
            dst[j]     = *(const bf8*)(s0 + j*16);
            dst[4 + j] = *(const bf8*)(s1 + j*16);
        }
    };

    f16v acc[2][4];
    #pragma unroll
    for (int mt = 0; mt < 2; mt++)
        #pragma unroll
        for (int ct = 0; ct < 4; ct++) {
            float bv = bias[ct*32 + l31];
            #pragma unroll
            for (int r = 0; r < 16; r++) acc[mt][ct][r] = bv;
        }

    // ---- prologue: W(0), probes, first gathers; full drain once ----
    stageW(0);
    int pA = probe(0);
    int pB = probe(1);
    int pr_old = probe(2);

    bf8 a_cur[8], a_next[8];
    {
        int g0 = __shfl(pA, l31, 64);
        int g1 = __shfl(pA, l31 + 32, 64);
        gather(g0, g1, a_cur);
    }
    int g0n = __shfl(pB, l31, 64);
    int g1n = __shfl(pB, l31 + 32, 64);

    __builtin_amdgcn_sched_barrier(0);
    asm volatile("s_waitcnt vmcnt(0)" ::: "memory");
    __builtin_amdgcn_s_barrier();

    #pragma unroll 1
    for (int ko = 0; ko < 27; ko++) {
        // stage first => the 4 LDS-DMA loads are the OLDEST vmem ops this iter
        if (ko < 26) {
            stageW(ko + 1);
            __builtin_amdgcn_sched_barrier(0);
            gather(g0n, g1n, a_next);        // 8 vmem, fly across the barrier
        }
        int pr_new = (ko < 24) ? probe(ko + 3) : -1;   // 1 vmem

        // ---- MFMA phase: a from regs, b from LDS buf (staged last iter) ----
        const int buf = ko & 1;
        #pragma unroll
        for (int ks = 0; ks < 4; ks++) {
            int jg = ks*2 + lhi;
            const short* wb = &Wlds[buf][(jg*128 + l31)*8];
            #pragma unroll
            for (int ct = 0; ct < 4; ct++) {
                bf8 b = *(const bf8*)(wb + ct*32*8);
                acc[0][ct] = __builtin_amdgcn_mfma_f32_32x32x16_bf16(a_cur[ks],     b, acc[0][ct], 0, 0, 0);
                acc[1][ct] = __builtin_amdgcn_mfma_f32_32x32x16_bf16(a_cur[4 + ks], b, acc[1][ct], 0, 0, 0);
            }
        }

        if (ko < 25) {                    // nids for data (ko+2), used next iter
            g0n = __shfl(pr_old, l31, 64);
            g1n = __shfl(pr_old, l31 + 32, 64);
            pr_old = pr_new;
        }
        #pragma unroll
        for (int j = 0; j < 8; j++) a_cur[j] = a_next[j];

        // counted wait: only the 4 stage loads (oldest) must land; gathers stay in flight
        if (ko < 26) {
            __builtin_amdgcn_sched_barrier(0);
            if (ko < 24) { asm volatile("s_waitcnt vmcnt(9)" ::: "memory"); }
            else         { asm volatile("s_waitcnt vmcnt(8)" ::: "memory"); }
            __builtin_amdgcn_s_barrier();
        }
    }

    // ---- epilogue: LSTM gates, lane-local; scatter to original point ids ----
    #pragma unroll
    for (int mt = 0; mt < 2; mt++) {
        #pragma unroll
        for (int r = 0; r < 16; r++) {
            int row = (r & 3) + 8*(r >> 2) + 4*lhi;
            int pp  = pbase + wv*64 + mt*32 + row;
            int opp = sorg[pp];
            float gi = acc[mt][0][r];
            float gf = acc[mt][1][r];
            float go = acc[mt][2][r];
            float gg = acc[mt][3][r];
            float cv = cfeat[opp*32 + l31];
            float si = fast_sigmoid(gi);
            float sf = fast_sigmoid(gf);
            float so = fast_sigmoid(go);
            float tg = fast_tanh(gg);
            float cn = sf*cv + si*tg;
            float hn = so * fast_tanh(cn);
            out[opp*32 + l31] = hn;
            out[N_PTS*32 + opp*32 + l31] = cn;
        }
    }
}

extern "C" void kernel_launch(void* const* d_in, const int* in_sizes, int n_in,
                              void* d_out, int out_size, void* d_ws, size_t ws_size,
                              hipStream_t stream) {
    const float* xf    = (const float*)d_in[0];
    const float* hf    = (const float*)d_in[1];
    const float* cf    = (const float*)d_in[2];
    const float* w     = (const float*)d_in[3];
    const float* bias  = (const float*)d_in[4];
    const int*   coors = (const int*)d_in[5];
    float* out = (float*)d_out;

    char* base = (char*)d_ws;
    int*   map    = (int*)base;                                        // 33554432 B
    short* fb     = (short*)(base + MAP_BYTES);                        // 67108864 B
    short* wtb    = (short*)(base + 100663296);                        //   442368 B
    short* zp     = (short*)(base + 101105664);                        //      512 B
    int*   sorg   = (int*)(base + 101106176);                          //  2097152 B
    int*   hist   = (int*)(base + 103203328);                          //    16384 B

    hipMemsetAsync(map, 0xFF, MAP_BYTES, stream);                      // map = -1
    hipMemsetAsync(hist, 0, NBKT*4, stream);
    hipMemsetAsync(zp, 0, 256, stream);                                // zero row
    k_feats<<<(N_PTS*8)/256, 256, 0, stream>>>(xf, hf, coors, hist, fb, map);
    k_scan<<<1, 256, 0, stream>>>(hist);
    k_rank<<<N_PTS/256, 256, 0, stream>>>(coors, hist, sorg);
    k_wt<<<(27*64*128 + 255)/256, 256, 0, stream>>>(w, wtb);
    k_main<<<N_PTS/256, 256, 0, stream>>>(map, fb, wtb, bias, cf, coors, sorg, zp, out);
}